// Round 1
// baseline (166.142 us; speedup 1.0000x reference)
//
#include <hip/hip_runtime.h>
#include <math.h>

#define B   8
#define S   256
#define NT  50
#define E   64
#define EPSF 1e-16f

__device__ __forceinline__ float softplus(float x) {
    // jax.nn.softplus = log1p(exp(x)); stable for large x
    if (x > 20.0f) return x;
    return log1pf(__expf(x));
}

__device__ __forceinline__ float wave_reduce_sum(float v) {
    #pragma unroll
    for (int off = 32; off > 0; off >>= 1)
        v += __shfl_down(v, off, 64);
    return v;  // lane 0 holds the sum
}

// ---------------------------------------------------------------------------
// LL term: one wave per (b, i). lane = embedding dim e.
// m[b,i,e] = sum_{j<i} emb_i * A[ty_j,ty_i,e] * exp(-emb_i*P[ty_j,ty_i,e]*emb_j*dt) * emb_j
// ll += log( sum_e softplus(emb_i*a_i + m) + EPS )   for valid i
// NOTE: m is NOT masked by validity of j (matches reference); only the outer
// ll sum is masked by valid i.
// ---------------------------------------------------------------------------
__global__ __launch_bounds__(64) void ll_kernel(
    const float* __restrict__ times, const int* __restrict__ types,
    const float* __restrict__ emb,  const float* __restrict__ a,
    const float* __restrict__ Amat, const float* __restrict__ Pmat,
    float* __restrict__ ll_acc)
{
    const int bid = blockIdx.x;
    const int b = bid / S;
    const int i = bid % S;
    const int e = threadIdx.x;

    __shared__ float s_t[S];
    __shared__ int   s_ty[S];
    for (int j = e; j < S; j += 64) {
        s_t[j]  = times[b * S + j];
        s_ty[j] = types[b * S + j];
    }
    __syncthreads();

    const float t_i  = s_t[i];
    const int   ty_i = s_ty[i];
    const float emb_i = emb[ty_i * E + e];
    const float a_i   = a[ty_i * E + e];

    float m = 0.0f;
    for (int j = 0; j < i; ++j) {
        const int   ty_j = s_ty[j];
        const float dt   = t_i - s_t[j];
        const int   base = (ty_j * NT + ty_i) * E + e;
        const float embj = emb[ty_j * E + e];
        const float Ae   = Amat[base];
        const float Pe   = Pmat[base];
        m += emb_i * Ae * __expf(-emb_i * Pe * embj * dt) * embj;
    }

    const float sp    = softplus(emb_i * a_i + m);
    const float inten = wave_reduce_sum(sp);
    if (e == 0 && t_i >= 0.0f) {
        atomicAdd(ll_acc, logf(inten + EPSF));
    }
}

// ---------------------------------------------------------------------------
// Integral term: one wave per (b, k). lane = embedding dim e.
// m_T[b,k,e] = sum_{valid i} emb_k * A[ty_i,k,e] * exp(-emb_k*P[ty_i,k,e]*emb_t_i*dT) * emb_t_i
// intenT[b] += sum_e softplus(emb_k*a_k + m_T)
// ---------------------------------------------------------------------------
__global__ __launch_bounds__(64) void integral_kernel(
    const float* __restrict__ times, const int* __restrict__ types,
    const int* __restrict__ Tp,
    const float* __restrict__ emb,  const float* __restrict__ a,
    const float* __restrict__ Amat, const float* __restrict__ Pmat,
    float* __restrict__ intenT)
{
    const int bid = blockIdx.x;
    const int b = bid / NT;
    const int k = bid % NT;
    const int e = threadIdx.x;
    const float Tf = (float)(*Tp);

    __shared__ float s_t[S];
    __shared__ int   s_ty[S];
    for (int j = e; j < S; j += 64) {
        s_t[j]  = times[b * S + j];
        s_ty[j] = types[b * S + j];
    }
    __syncthreads();

    const float embk = emb[k * E + e];
    const float ak   = a[k * E + e];

    float mT = 0.0f;
    for (int i = 0; i < S; ++i) {
        const float t_i = s_t[i];
        if (t_i < 0.0f) continue;  // m_T masks invalid events
        const int   ty   = s_ty[i];
        const float embt = emb[ty * E + e];
        const int   idx  = (ty * NT + k) * E + e;
        const float dT   = Tf - t_i;
        mT += embk * Amat[idx] * __expf(-embk * Pmat[idx] * embt * dT) * embt;
    }

    const float sp = softplus(embk * ak + mT);
    const float s  = wave_reduce_sum(sp);
    if (e == 0) atomicAdd(&intenT[b], s);
}

// ---------------------------------------------------------------------------
// Finalize: base_sum, per-batch first/last valid time, combine to scalar.
// out = integral - ll
// ---------------------------------------------------------------------------
__global__ __launch_bounds__(256) void finalize_kernel(
    const float* __restrict__ times,
    const int* __restrict__ Tp,
    const float* __restrict__ emb, const float* __restrict__ a,
    const float* __restrict__ ll_acc, const float* __restrict__ intenT,
    float* __restrict__ out)
{
    const int t = threadIdx.x;
    const float Tf = (float)(*Tp);

    // base_sum = sum softplus(emb * a) over NT*E
    float bs = 0.0f;
    for (int idx = t; idx < NT * E; idx += 256) {
        bs += softplus(emb[idx] * a[idx]);
    }
    __shared__ float red[256];
    red[t] = bs;
    __syncthreads();
    for (int off = 128; off > 0; off >>= 1) {
        if (t < off) red[t] += red[t + off];
        __syncthreads();
    }
    __shared__ float s_base;
    if (t == 0) s_base = red[0];
    __syncthreads();
    const float base_sum = s_base;

    __shared__ float rmin[256], rmax[256];
    __shared__ float s_integral;
    if (t == 0) s_integral = 0.0f;
    __syncthreads();

    for (int b = 0; b < B; ++b) {
        const float tv = times[b * S + t];
        const bool valid = (tv >= 0.0f);
        rmin[t] = valid ? tv : 1e30f;
        rmax[t] = valid ? tv : -1e30f;
        __syncthreads();
        for (int off = 128; off > 0; off >>= 1) {
            if (t < off) {
                rmin[t] = fminf(rmin[t], rmin[t + off]);
                rmax[t] = fmaxf(rmax[t], rmax[t + off]);
            }
            __syncthreads();
        }
        if (t == 0) {
            const bool any_valid = (rmin[0] < 1e29f);
            const float first = any_valid ? rmin[0] : 0.0f;
            const float last  = any_valid ? rmax[0] : 0.0f;
            const float ib = any_valid
                ? intenT[b] * (Tf - last) + base_sum * first
                : base_sum * Tf;
            s_integral += ib;
        }
        __syncthreads();
    }

    if (t == 0) {
        out[0] = s_integral - ll_acc[0];
    }
}

__global__ void zero_kernel(float* __restrict__ ws) {
    if (threadIdx.x < 16) ws[threadIdx.x] = 0.0f;
}

extern "C" void kernel_launch(void* const* d_in, const int* in_sizes, int n_in,
                              void* d_out, int out_size, void* d_ws, size_t ws_size,
                              hipStream_t stream) {
    const float* times = (const float*)d_in[0];
    const int*   types = (const int*)d_in[1];
    const int*   Tp    = (const int*)d_in[2];
    const float* emb   = (const float*)d_in[3];
    const float* a     = (const float*)d_in[4];
    const float* Amat  = (const float*)d_in[5];
    const float* Pmat  = (const float*)d_in[6];

    float* ws     = (float*)d_ws;
    float* ll_acc = ws;        // ws[0]
    float* intenT = ws + 1;    // ws[1..8]
    float* out    = (float*)d_out;

    zero_kernel<<<1, 64, 0, stream>>>(ws);
    ll_kernel<<<B * S, 64, 0, stream>>>(times, types, emb, a, Amat, Pmat, ll_acc);
    integral_kernel<<<B * NT, 64, 0, stream>>>(times, types, Tp, emb, a, Amat, Pmat, intenT);
    finalize_kernel<<<1, 256, 0, stream>>>(times, Tp, emb, a, ll_acc, intenT, out);
}

// Round 2
// 130.256 us; speedup vs baseline: 1.2755x; 1.2755x over previous
//
#include <hip/hip_runtime.h>
#include <math.h>

#define B   8
#define S   256
#define NT  50
#define E   64
#define EPSF 1e-16f

__device__ __forceinline__ float softplus(float x) {
    if (x > 20.0f) return x;
    return log1pf(__expf(x));
}

__device__ __forceinline__ float wave_reduce_sum(float v) {
    #pragma unroll
    for (int off = 32; off > 0; off >>= 1)
        v += __shfl_down(v, off, 64);
    return v;  // lane 0 holds the sum
}

// ---------------------------------------------------------------------------
// LL term: one block (4 waves) per (b, i). lane = embedding dim e; the 4
// waves split the j-loop (stride 4) so their A/P loads pipeline. Partial m
// reduced through LDS; wave 0 does softplus + log + atomic.
// m[b,i,e] = sum_{j<i} emb_i * A[ty_j,ty_i,e] * exp(-emb_i*P[ty_j,ty_i,e]*emb_j*dt) * emb_j
// (m is NOT masked by validity of j — matches reference; only outer ll sum is.)
// ---------------------------------------------------------------------------
#define LL_NW 4
__global__ __launch_bounds__(64 * LL_NW) void ll_kernel(
    const float* __restrict__ times, const int* __restrict__ types,
    const float* __restrict__ emb,  const float* __restrict__ a,
    const float* __restrict__ Amat, const float* __restrict__ Pmat,
    float* __restrict__ ll_acc)
{
    const int b = blockIdx.x / S;
    const int i = blockIdx.x % S;
    const int tid = threadIdx.x;
    const int e = tid & 63;
    const int w = tid >> 6;

    __shared__ float s_t[S];
    __shared__ int   s_ty[S];
    __shared__ float s_emb[NT * E];          // 12.8 KB, stride-1 over lanes -> conflict-free
    __shared__ float s_part[LL_NW][E];

    for (int j = tid; j < S; j += 64 * LL_NW) {
        s_t[j]  = times[b * S + j];
        s_ty[j] = types[b * S + j];
    }
    for (int idx = tid; idx < NT * E; idx += 64 * LL_NW)
        s_emb[idx] = emb[idx];
    __syncthreads();

    const float t_i   = s_t[i];
    const int   ty_i  = s_ty[i];
    const float emb_i = s_emb[ty_i * E + e];

    float m = 0.0f;
    for (int j = w; j < i; j += LL_NW) {
        const int   ty_j = s_ty[j];
        const float dt   = t_i - s_t[j];
        const int   base = (ty_j * NT + ty_i) * E + e;
        const float embj = s_emb[ty_j * E + e];
        const float Ae   = Amat[base];
        const float Pe   = Pmat[base];
        m += emb_i * Ae * __expf(-emb_i * Pe * embj * dt) * embj;
    }
    s_part[w][e] = m;
    __syncthreads();

    if (w == 0) {
        float mt = 0.0f;
        #pragma unroll
        for (int q = 0; q < LL_NW; ++q) mt += s_part[q][e];
        const float a_i   = a[ty_i * E + e];
        const float sp    = softplus(emb_i * a_i + mt);
        const float inten = wave_reduce_sum(sp);
        if (e == 0 && t_i >= 0.0f)
            atomicAdd(ll_acc, logf(inten + EPSF));
    }
}

// ---------------------------------------------------------------------------
// Integral term: one block (8 waves) per (b, k). Waves split the i-loop
// (stride 8); partial m_T reduced through LDS; wave 0 does softplus + atomic.
// m_T[b,k,e] = sum_{valid i} emb_k * A[ty_i,k,e] * exp(-emb_k*P[ty_i,k,e]*emb_t_i*dT) * emb_t_i
// ---------------------------------------------------------------------------
#define IN_NW 8
__global__ __launch_bounds__(64 * IN_NW) void integral_kernel(
    const float* __restrict__ times, const int* __restrict__ types,
    const int* __restrict__ Tp,
    const float* __restrict__ emb,  const float* __restrict__ a,
    const float* __restrict__ Amat, const float* __restrict__ Pmat,
    float* __restrict__ intenT)
{
    const int b = blockIdx.x / NT;
    const int k = blockIdx.x % NT;
    const int tid = threadIdx.x;
    const int e = tid & 63;
    const int w = tid >> 6;
    const float Tf = (float)(*Tp);

    __shared__ float s_t[S];
    __shared__ int   s_ty[S];
    __shared__ float s_emb[NT * E];
    __shared__ float s_part[IN_NW][E];

    for (int j = tid; j < S; j += 64 * IN_NW) {
        s_t[j]  = times[b * S + j];
        s_ty[j] = types[b * S + j];
    }
    for (int idx = tid; idx < NT * E; idx += 64 * IN_NW)
        s_emb[idx] = emb[idx];
    __syncthreads();

    const float embk = s_emb[k * E + e];

    float mT = 0.0f;
    for (int i = w; i < S; i += IN_NW) {
        const float t_i = s_t[i];
        if (t_i < 0.0f) continue;  // m_T masks invalid events
        const int   ty   = s_ty[i];
        const float embt = s_emb[ty * E + e];
        const int   idx  = (ty * NT + k) * E + e;
        const float dT   = Tf - t_i;
        mT += embk * Amat[idx] * __expf(-embk * Pmat[idx] * embt * dT) * embt;
    }
    s_part[w][e] = mT;
    __syncthreads();

    if (w == 0) {
        float mt = 0.0f;
        #pragma unroll
        for (int q = 0; q < IN_NW; ++q) mt += s_part[q][e];
        const float ak = a[k * E + e];
        const float sp = softplus(embk * ak + mt);
        const float s  = wave_reduce_sum(sp);
        if (e == 0) atomicAdd(&intenT[b], s);
    }
}

// ---------------------------------------------------------------------------
// Finalize: base_sum, per-batch first/last valid time, combine to scalar.
// out = integral - ll
// ---------------------------------------------------------------------------
__global__ __launch_bounds__(256) void finalize_kernel(
    const float* __restrict__ times,
    const int* __restrict__ Tp,
    const float* __restrict__ emb, const float* __restrict__ a,
    const float* __restrict__ ll_acc, const float* __restrict__ intenT,
    float* __restrict__ out)
{
    const int t = threadIdx.x;
    const float Tf = (float)(*Tp);

    float bs = 0.0f;
    for (int idx = t; idx < NT * E; idx += 256)
        bs += softplus(emb[idx] * a[idx]);

    __shared__ float red[256];
    red[t] = bs;
    __syncthreads();
    for (int off = 128; off > 0; off >>= 1) {
        if (t < off) red[t] += red[t + off];
        __syncthreads();
    }
    __shared__ float s_base;
    if (t == 0) s_base = red[0];
    __syncthreads();
    const float base_sum = s_base;

    __shared__ float rmin[256], rmax[256];
    __shared__ float s_integral;
    if (t == 0) s_integral = 0.0f;
    __syncthreads();

    for (int b = 0; b < B; ++b) {
        const float tv = times[b * S + t];
        const bool valid = (tv >= 0.0f);
        rmin[t] = valid ? tv : 1e30f;
        rmax[t] = valid ? tv : -1e30f;
        __syncthreads();
        for (int off = 128; off > 0; off >>= 1) {
            if (t < off) {
                rmin[t] = fminf(rmin[t], rmin[t + off]);
                rmax[t] = fmaxf(rmax[t], rmax[t + off]);
            }
            __syncthreads();
        }
        if (t == 0) {
            const bool any_valid = (rmin[0] < 1e29f);
            const float first = any_valid ? rmin[0] : 0.0f;
            const float last  = any_valid ? rmax[0] : 0.0f;
            const float ib = any_valid
                ? intenT[b] * (Tf - last) + base_sum * first
                : base_sum * Tf;
            s_integral += ib;
        }
        __syncthreads();
    }

    if (t == 0)
        out[0] = s_integral - ll_acc[0];
}

__global__ void zero_kernel(float* __restrict__ ws) {
    if (threadIdx.x < 16) ws[threadIdx.x] = 0.0f;
}

extern "C" void kernel_launch(void* const* d_in, const int* in_sizes, int n_in,
                              void* d_out, int out_size, void* d_ws, size_t ws_size,
                              hipStream_t stream) {
    const float* times = (const float*)d_in[0];
    const int*   types = (const int*)d_in[1];
    const int*   Tp    = (const int*)d_in[2];
    const float* emb   = (const float*)d_in[3];
    const float* a     = (const float*)d_in[4];
    const float* Amat  = (const float*)d_in[5];
    const float* Pmat  = (const float*)d_in[6];

    float* ws     = (float*)d_ws;
    float* ll_acc = ws;        // ws[0]
    float* intenT = ws + 1;    // ws[1..8]
    float* out    = (float*)d_out;

    zero_kernel<<<1, 64, 0, stream>>>(ws);
    ll_kernel<<<B * S, 64 * LL_NW, 0, stream>>>(times, types, emb, a, Amat, Pmat, ll_acc);
    integral_kernel<<<B * NT, 64 * IN_NW, 0, stream>>>(times, types, Tp, emb, a, Amat, Pmat, intenT);
    finalize_kernel<<<1, 256, 0, stream>>>(times, Tp, emb, a, ll_acc, intenT, out);
}

// Round 3
// 98.398 us; speedup vs baseline: 1.6885x; 1.3238x over previous
//
#include <hip/hip_runtime.h>
#include <math.h>

#define B   8
#define S   256
#define NT  50
#define E   64
#define EPSF 1e-16f

#define NW        4                 // waves per block
#define LL_BLOCKS (B * S / 2)       // 1024 blocks; each handles rows (i, S-1-i)
#define IN_BLOCKS (B * NT)          // 400 blocks

__device__ __forceinline__ float softplus(float x) {
    if (x > 20.0f) return x;
    return log1pf(__expf(x));
}

__device__ __forceinline__ float wave_reduce_sum(float v) {
    #pragma unroll
    for (int off = 32; off > 0; off >>= 1)
        v += __shfl_down(v, off, 64);
    return v;  // lane 0 holds the sum
}

// ---------------------------------------------------------------------------
// Fused kernel. Grid = LL_BLOCKS + IN_BLOCKS, 256 threads (4 waves).
//
// LL blocks (bid < LL_BLOCKS): block handles batch b = bid/128 and the row
// pair (ih, 255-ih) — total inner iterations ih + (255-ih) = 255 per block,
// perfectly balanced. The 4 waves split each row's j-loop (stride 4);
// partials reduced through LDS; waves 0/1 finish rows 0/1 in parallel.
//   m[b,i,e] = sum_{j<i} emb_i * A[ty_j,ty_i,e]
//              * exp(-emb_i*P[ty_j,ty_i,e]*emb_j*(t_i-t_j)) * emb_j
//   ws_ll[bid] = sum over the 2 rows of (valid_i ? log(sum_e softplus(...)+EPS) : 0)
// (m is NOT masked by j-validity — matches reference.)
//
// Integral blocks: (b,k) per block, 4 waves split the i-loop.
//   m_T[b,k,e] = sum_{valid i} emb_k*A[ty_i,k,e]
//                * exp(-emb_k*P[ty_i,k,e]*emb_i*(T-t_i)) * emb_i
//   ws_int[(b,k)] = sum_e softplus(emb_k*a_k + m_T)
// ---------------------------------------------------------------------------
__global__ __launch_bounds__(64 * NW) void main_kernel(
    const float* __restrict__ times, const int* __restrict__ types,
    const int* __restrict__ Tp,
    const float* __restrict__ emb,  const float* __restrict__ a,
    const float* __restrict__ Amat, const float* __restrict__ Pmat,
    float* __restrict__ ws_ll, float* __restrict__ ws_int)
{
    const int tid = threadIdx.x;
    const int e   = tid & 63;
    const int w   = tid >> 6;
    const int bid = blockIdx.x;
    const bool is_ll = (bid < LL_BLOCKS);
    const int b = is_ll ? (bid / (S / 2)) : ((bid - LL_BLOCKS) / NT);

    __shared__ float s_emb[NT * E];        // 12.8 KB, lane-contiguous reads
    __shared__ float s_t[S];
    __shared__ int   s_ty[S];
    __shared__ float s_part[2][NW][E];
    __shared__ float s_row[2];

    for (int idx = tid; idx < NT * E; idx += 64 * NW)
        s_emb[idx] = emb[idx];
    for (int j = tid; j < S; j += 64 * NW) {
        s_t[j]  = times[b * S + j];
        s_ty[j] = types[b * S + j];
    }
    __syncthreads();

    if (is_ll) {
        const int ih = bid % (S / 2);
        const int rows[2] = { ih, S - 1 - ih };
        #pragma unroll
        for (int r = 0; r < 2; ++r) {
            const int   i     = rows[r];
            const float t_i   = s_t[i];
            const int   ty_i  = s_ty[i];
            const float emb_i = s_emb[ty_i * E + e];
            float m = 0.0f;
            #pragma unroll 4
            for (int j = w; j < i; j += NW) {
                const int   ty_j = s_ty[j];
                const float dt   = t_i - s_t[j];
                const int   base = (ty_j * NT + ty_i) * E + e;
                const float embj = s_emb[ty_j * E + e];
                m += emb_i * Amat[base] * __expf(-emb_i * Pmat[base] * embj * dt) * embj;
            }
            s_part[r][w][e] = m;
        }
        __syncthreads();
        if (w < 2) {
            const int   i     = rows[w];
            const float t_i   = s_t[i];
            const int   ty_i  = s_ty[i];
            const float emb_i = s_emb[ty_i * E + e];
            float mt = 0.0f;
            #pragma unroll
            for (int q = 0; q < NW; ++q) mt += s_part[w][q][e];
            const float sp    = softplus(emb_i * a[ty_i * E + e] + mt);
            const float inten = wave_reduce_sum(sp);
            if (e == 0)
                s_row[w] = (t_i >= 0.0f) ? logf(inten + EPSF) : 0.0f;
        }
        __syncthreads();
        if (tid == 0) ws_ll[bid] = s_row[0] + s_row[1];
    } else {
        const int   k    = (bid - LL_BLOCKS) % NT;
        const float Tf   = (float)(*Tp);
        const float embk = s_emb[k * E + e];
        float mT = 0.0f;
        #pragma unroll 4
        for (int i = w; i < S; i += NW) {
            const float t_i  = s_t[i];
            const int   ty   = s_ty[i];
            const float embt = s_emb[ty * E + e];
            const int   idx  = (ty * NT + k) * E + e;
            const float c = embk * Amat[idx]
                          * __expf(-embk * Pmat[idx] * embt * (Tf - t_i)) * embt;
            mT += (t_i >= 0.0f) ? c : 0.0f;   // predicated, no branch
        }
        s_part[0][w][e] = mT;
        __syncthreads();
        if (w == 0) {
            float mt = 0.0f;
            #pragma unroll
            for (int q = 0; q < NW; ++q) mt += s_part[0][q][e];
            const float sp = softplus(embk * a[k * E + e] + mt);
            const float s  = wave_reduce_sum(sp);
            if (e == 0) ws_int[bid - LL_BLOCKS] = s;
        }
    }
}

// ---------------------------------------------------------------------------
// Finalize: sum ll partials (1024), per-batch integral partials (8×50),
// base_sum, first/last valid time, combine. out = integral - ll.
// ---------------------------------------------------------------------------
__global__ __launch_bounds__(256) void finalize_kernel(
    const float* __restrict__ times,
    const int* __restrict__ Tp,
    const float* __restrict__ emb, const float* __restrict__ a,
    const float* __restrict__ ws_ll, const float* __restrict__ ws_int,
    float* __restrict__ out)
{
    const int t = threadIdx.x;
    const float Tf = (float)(*Tp);

    // --- ll total + base_sum (fused strided accumulation) ---
    float llp = 0.0f;
    for (int idx = t; idx < LL_BLOCKS; idx += 256) llp += ws_ll[idx];
    float bs = 0.0f;
    for (int idx = t; idx < NT * E; idx += 256) bs += softplus(emb[idx] * a[idx]);

    __shared__ float red[256], red2[256];
    red[t] = llp; red2[t] = bs;
    __syncthreads();
    for (int off = 128; off > 0; off >>= 1) {
        if (t < off) { red[t] += red[t + off]; red2[t] += red2[t + off]; }
        __syncthreads();
    }
    __shared__ float s_ll, s_base;
    if (t == 0) { s_ll = red[0]; s_base = red2[0]; }
    __syncthreads();
    const float base_sum = s_base;

    // --- intenT[b]: 32 lanes per batch sum its 50 partials ---
    __shared__ float s_intenT[B];
    {
        const int bb   = t >> 5;      // 0..7
        const int lane = t & 31;
        float v = 0.0f;
        for (int k = lane; k < NT; k += 32) v += ws_int[bb * NT + k];
        #pragma unroll
        for (int off = 16; off > 0; off >>= 1)
            v += __shfl_down(v, off, 32);
        if (lane == 0) s_intenT[bb] = v;
    }
    __syncthreads();

    // --- per-batch first/last valid time + combine ---
    __shared__ float rmin[256], rmax[256];
    __shared__ float s_integral;
    if (t == 0) s_integral = 0.0f;
    __syncthreads();

    for (int b = 0; b < B; ++b) {
        const float tv = times[b * S + t];
        const bool valid = (tv >= 0.0f);
        rmin[t] = valid ? tv : 1e30f;
        rmax[t] = valid ? tv : -1e30f;
        __syncthreads();
        for (int off = 128; off > 0; off >>= 1) {
            if (t < off) {
                rmin[t] = fminf(rmin[t], rmin[t + off]);
                rmax[t] = fmaxf(rmax[t], rmax[t + off]);
            }
            __syncthreads();
        }
        if (t == 0) {
            const bool any_valid = (rmin[0] < 1e29f);
            const float first = any_valid ? rmin[0] : 0.0f;
            const float last  = any_valid ? rmax[0] : 0.0f;
            const float ib = any_valid
                ? s_intenT[b] * (Tf - last) + base_sum * first
                : base_sum * Tf;
            s_integral += ib;
        }
        __syncthreads();
    }

    if (t == 0)
        out[0] = s_integral - s_ll;
}

extern "C" void kernel_launch(void* const* d_in, const int* in_sizes, int n_in,
                              void* d_out, int out_size, void* d_ws, size_t ws_size,
                              hipStream_t stream) {
    const float* times = (const float*)d_in[0];
    const int*   types = (const int*)d_in[1];
    const int*   Tp    = (const int*)d_in[2];
    const float* emb   = (const float*)d_in[3];
    const float* a     = (const float*)d_in[4];
    const float* Amat  = (const float*)d_in[5];
    const float* Pmat  = (const float*)d_in[6];

    float* ws     = (float*)d_ws;
    float* ws_ll  = ws;                  // [0, 1024)
    float* ws_int = ws + LL_BLOCKS;      // [1024, 1424)
    float* out    = (float*)d_out;

    main_kernel<<<LL_BLOCKS + IN_BLOCKS, 64 * NW, 0, stream>>>(
        times, types, Tp, emb, a, Amat, Pmat, ws_ll, ws_int);
    finalize_kernel<<<1, 256, 0, stream>>>(times, Tp, emb, a, ws_ll, ws_int, out);
}

// Round 4
// 89.436 us; speedup vs baseline: 1.8577x; 1.1002x over previous
//
#include <hip/hip_runtime.h>
#include <math.h>

#define B   8
#define S   256
#define NT  50
#define E   64
#define NTE (NT * E)
#define EPSF 1e-16f

#define NW        4                 // waves per block
#define LL_BLOCKS (B * S / 2)       // 1024 blocks; each handles rows (ih, S-1-ih)
#define IN_BLOCKS (B * NT)          // 400 blocks

__device__ __forceinline__ float softplus(float x) {
    if (x > 20.0f) return x;
    return log1pf(__expf(x));
}

__device__ __forceinline__ float wave_reduce_sum(float v) {
    #pragma unroll
    for (int off = 32; off > 0; off >>= 1)
        v += __shfl_down(v, off, 64);
    return v;  // lane 0 holds the sum
}

// ---------------------------------------------------------------------------
// Fused main kernel. Grid = LL_BLOCKS + IN_BLOCKS, 256 threads (4 waves).
//
// LL blocks: block handles batch b and the row pair (ih, 255-ih) -> uniform
// 255 inner iterations per block (perfect balance). Waves split each row's
// j-loop stride-4. Inner product hoisted: m = emb_i * sum_j A*ej*exp(...).
//   ws_ll[bid] = sum over 2 rows of (valid_i ? log(sum_e softplus(...)+EPS) : 0)
// (m is NOT masked by j-validity; only outer ll sum is — matches reference.)
//
// Integral blocks: (b,k) per block, waves split the i-loop, invalid events
// predicated out.  ws_int[(b,k)] = sum_e softplus(emb_k*a_k + m_T).
// ---------------------------------------------------------------------------
__global__ __launch_bounds__(64 * NW) void main_kernel(
    const float* __restrict__ times, const int* __restrict__ types,
    const int* __restrict__ Tp,
    const float* __restrict__ emb,  const float* __restrict__ a,
    const float* __restrict__ Amat, const float* __restrict__ Pmat,
    float* __restrict__ ws_ll, float* __restrict__ ws_int)
{
    const int tid = threadIdx.x;
    const int e   = tid & 63;
    const int w   = tid >> 6;
    const int bid = blockIdx.x;
    const bool is_ll = (bid < LL_BLOCKS);
    const int b = is_ll ? (bid / (S / 2)) : ((bid - LL_BLOCKS) / NT);

    __shared__ __align__(16) float s_emb[NTE];   // 12.8 KB, lane-contiguous
    __shared__ float2 s_ev[S];                   // (time, as_float(type))
    __shared__ float  s_part[2][NW][E];
    __shared__ float  s_row[2];

    // stage emb with float4 (800 vec4 loads across 256 threads)
    {
        const float4* __restrict__ emb4 = (const float4*)emb;
        float4* s4 = (float4*)s_emb;
        for (int idx = tid; idx < NTE / 4; idx += 64 * NW)
            s4[idx] = emb4[idx];
    }
    for (int j = tid; j < S; j += 64 * NW)
        s_ev[j] = make_float2(times[b * S + j], __int_as_float(types[b * S + j]));
    __syncthreads();

    if (is_ll) {
        const int ih = bid % (S / 2);
        const int rows[2] = { ih, S - 1 - ih };
        #pragma unroll
        for (int r = 0; r < 2; ++r) {
            const int   i     = rows[r];
            const float t_i   = s_ev[i].x;
            const int   ty_i  = __float_as_int(s_ev[i].y);
            const int   col   = ty_i * E + e;
            const float negEi = -s_emb[col];

            float macc = 0.0f;
            #pragma unroll 8
            for (int j = w; j < i; j += NW) {
                const float2 ev  = s_ev[j];
                const int   tyj  = __float_as_int(ev.y);
                const float dtj  = t_i - ev.x;
                const int   base = tyj * NTE + col;
                const float ej   = s_emb[tyj * E + e];
                const float Pe   = Pmat[base];
                const float Ae   = Amat[base];
                macc = fmaf(Ae * ej, __expf(negEi * Pe * ej * dtj), macc);
            }
            s_part[r][w][e] = macc;
        }
        __syncthreads();
        if (w < 2) {
            const int   i     = rows[w];
            const float t_i   = s_ev[i].x;
            const int   ty_i  = __float_as_int(s_ev[i].y);
            const int   col   = ty_i * E + e;
            const float emb_i = s_emb[col];
            float mt = 0.0f;
            #pragma unroll
            for (int q = 0; q < NW; ++q) mt += s_part[w][q][e];
            const float sp    = softplus(fmaf(emb_i, mt, emb_i * a[col]));
            const float inten = wave_reduce_sum(sp);
            if (e == 0)
                s_row[w] = (t_i >= 0.0f) ? logf(inten + EPSF) : 0.0f;
        }
        __syncthreads();
        if (tid == 0) ws_ll[bid] = s_row[0] + s_row[1];
    } else {
        const int   k    = (bid - LL_BLOCKS) % NT;
        const float Tf   = (float)(*Tp);
        const int   colk = k * E + e;
        const float embk = s_emb[colk];
        const float negEk = -embk;

        float acc = 0.0f;
        #pragma unroll 8
        for (int i = w; i < S; i += NW) {
            const float2 ev  = s_ev[i];
            const int   ty   = __float_as_int(ev.y);
            const float dT   = Tf - ev.x;
            const int   base = ty * NTE + colk;
            const float et   = s_emb[ty * E + e];
            const float c    = Amat[base] * et * __expf(negEk * Pmat[base] * et * dT);
            acc += (ev.x >= 0.0f) ? c : 0.0f;   // predicated, no branch
        }
        s_part[0][w][e] = acc;
        __syncthreads();
        if (w == 0) {
            float mt = 0.0f;
            #pragma unroll
            for (int q = 0; q < NW; ++q) mt += s_part[0][q][e];
            const float sp = softplus(fmaf(embk, mt, embk * a[colk]));
            const float s  = wave_reduce_sum(sp);
            if (e == 0) ws_int[bid - LL_BLOCKS] = s;
        }
    }
}

// ---------------------------------------------------------------------------
// Finalize: one block, 4 waves. Tree-reduce ll partials + base_sum via LDS;
// per-batch min/max/intenT via one wave each (shuffle reductions, no trees).
// out = integral - ll
// ---------------------------------------------------------------------------
__global__ __launch_bounds__(256) void finalize_kernel(
    const float* __restrict__ times,
    const int* __restrict__ Tp,
    const float* __restrict__ emb, const float* __restrict__ a,
    const float* __restrict__ ws_ll, const float* __restrict__ ws_int,
    float* __restrict__ out)
{
    const int t    = threadIdx.x;
    const int lane = t & 63;
    const int w    = t >> 6;
    const float Tf = (float)(*Tp);

    // strided partial sums: ll (1024 entries) and base_sum (3200 entries)
    float llp = 0.0f;
    for (int idx = t; idx < LL_BLOCKS; idx += 256) llp += ws_ll[idx];
    float bs = 0.0f;
    for (int idx = t; idx < NTE; idx += 256) bs += softplus(emb[idx] * a[idx]);

    __shared__ float red[256], red2[256];
    red[t] = llp; red2[t] = bs;

    // per-batch first/last valid time + intenT, one wave per 2 batches
    __shared__ float s_first[B], s_last[B], s_iT[B], s_any[B];
    for (int b = w; b < B; b += 4) {
        float mn = 1e30f, mx = -1e30f;
        #pragma unroll
        for (int q = 0; q < S / 64; ++q) {
            const float tv = times[b * S + q * 64 + lane];
            const bool valid = (tv >= 0.0f);
            mn = fminf(mn, valid ? tv : 1e30f);
            mx = fmaxf(mx, valid ? tv : -1e30f);
        }
        float iv = (lane < NT) ? ws_int[b * NT + lane] : 0.0f;
        #pragma unroll
        for (int off = 32; off > 0; off >>= 1) {
            mn = fminf(mn, __shfl_down(mn, off, 64));
            mx = fmaxf(mx, __shfl_down(mx, off, 64));
            iv += __shfl_down(iv, off, 64);
        }
        if (lane == 0) {
            const bool any_valid = (mn < 1e29f);
            s_any[b]   = any_valid ? 1.0f : 0.0f;
            s_first[b] = any_valid ? mn : 0.0f;
            s_last[b]  = any_valid ? mx : 0.0f;
            s_iT[b]    = iv;
        }
    }
    __syncthreads();

    for (int off = 128; off > 0; off >>= 1) {
        if (t < off) { red[t] += red[t + off]; red2[t] += red2[t + off]; }
        __syncthreads();
    }

    if (t == 0) {
        const float base_sum = red2[0];
        float integral = 0.0f;
        #pragma unroll
        for (int b = 0; b < B; ++b) {
            integral += (s_any[b] > 0.5f)
                ? s_iT[b] * (Tf - s_last[b]) + base_sum * s_first[b]
                : base_sum * Tf;
        }
        out[0] = integral - red[0];
    }
}

extern "C" void kernel_launch(void* const* d_in, const int* in_sizes, int n_in,
                              void* d_out, int out_size, void* d_ws, size_t ws_size,
                              hipStream_t stream) {
    const float* times = (const float*)d_in[0];
    const int*   types = (const int*)d_in[1];
    const int*   Tp    = (const int*)d_in[2];
    const float* emb   = (const float*)d_in[3];
    const float* a     = (const float*)d_in[4];
    const float* Amat  = (const float*)d_in[5];
    const float* Pmat  = (const float*)d_in[6];

    float* ws     = (float*)d_ws;
    float* ws_ll  = ws;                  // [0, 1024)
    float* ws_int = ws + LL_BLOCKS;      // [1024, 1424)
    float* out    = (float*)d_out;

    main_kernel<<<LL_BLOCKS + IN_BLOCKS, 64 * NW, 0, stream>>>(
        times, types, Tp, emb, a, Amat, Pmat, ws_ll, ws_int);
    finalize_kernel<<<1, 256, 0, stream>>>(times, Tp, emb, a, ws_ll, ws_int, out);
}